// Round 14
// baseline (236.609 us; speedup 1.0000x reference)
//
#include <hip/hip_runtime.h>
#include <stdint.h>

typedef short bf16x8 __attribute__((ext_vector_type(8)));
typedef float f32x4  __attribute__((ext_vector_type(4)));

#define GLOAD_LDS16(gp, lp) \
    __builtin_amdgcn_global_load_lds((const __attribute__((address_space(1))) void*)(gp), \
                                     (__attribute__((address_space(3))) void*)(lp), 16, 0, 0)

__device__ __forceinline__ uint32_t bfbits(float f) {
    uint32_t u = __builtin_bit_cast(uint32_t, f);
    u += 0x7FFFu + ((u >> 16) & 1u);   // round-to-nearest-even
    return u >> 16;
}
__device__ __forceinline__ uint32_t pk2(float a, float b) {
    return bfbits(a) | (bfbits(b) << 16);
}

// Fused prep: blocks [0,2048) convert x -> xb (bf16, PADDED [16][194][194][64],
// zero halo, nontemporal x loads); blocks [2048,2624) build
// Wt[t][c][j][ic] = bf16(W[dy][dx][ic][j*4+c]).
__global__ void prep_kernel(const float* __restrict__ x, short* __restrict__ xb,
                            const float* __restrict__ W, short* __restrict__ Wt) {
    const int b = blockIdx.x;
    if (b < 2048) {
        const int total = 16 * 194 * 194 * 8;          // 16B chunks
        for (int i = b * 256 + threadIdx.x; i < total; i += 2048 * 256) {
            int g  = i & 7;
            int t  = i >> 3;
            int wp = t % 194; t /= 194;
            int hp = t % 194;
            int nn = t / 194;
            uint4 r = {0u, 0u, 0u, 0u};
            if (hp >= 1 && hp <= 192 && wp >= 1 && wp <= 192) {
                const float* s = x + (((size_t)nn * 192 + (hp - 1)) * 192 + (wp - 1)) * 64 + g * 8;
                f32x4 a = __builtin_nontemporal_load((const f32x4*)s);
                f32x4 bb = __builtin_nontemporal_load((const f32x4*)(s + 4));
                r.x = pk2(a[0], a[1]); r.y = pk2(a[2], a[3]);
                r.z = pk2(bb[0], bb[1]); r.w = pk2(bb[2], bb[3]);
            }
            *(uint4*)(xb + (size_t)i * 8) = r;
        }
    } else {
        int idx = (b - 2048) * 256 + threadIdx.x;      // 147456
        if (idx < 147456) {
            int t  = idx >> 14;
            int r  = idx & 16383;
            int c  = r >> 12;
            int j  = (r >> 6) & 63;
            int ic = r & 63;
            Wt[idx] = (short)bfbits(W[(t * 64 + ic) * 256 + j * 4 + c]);
        }
    }
}

#define NRING 7
#define ASLOT_B 8448                     // bytes per A h-row slot (66*64*2)
#define B_OFF   (NRING * ASLOT_B)        // 59,136 : B dbuf starts here
#define SMEM_SHORTS ((B_OFF + 2 * 8192) / 2)   // 75,520 B total -> 2 blocks/CU

// Implicit-GEMM conv3x3 + bias + pixel_shuffle quadrant, bf16 MFMA.
// 256 thr = 4 waves; wave = 1 h-row x 64 w x 64 j (0.5 ds_read/MFMA).
// B streamed per-tap from L2-resident Wt through a 2x8KB LDS dbuf; A-ring of
// 7 slots with per-tap scheduled refills. Counted vmcnt per tap (never 0,
// never drains stores). TWO barriers per tap (m201 pattern): tap-start
// barrier = LDS-overwrite safety; post-vmcnt barrier = cross-wave DMA
// completion (vmcnt is per-wave — r13's missing barrier was the race).
__global__ __launch_bounds__(256, 2) void conv_ps_kernel(
    const short* __restrict__ xb, const short* __restrict__ Wt,
    const float* __restrict__ bias, float* __restrict__ out)
{
    __shared__ short smem[SMEM_SHORTS];

    const int tid   = threadIdx.x;
    const int lane  = tid & 63;
    const int wv    = tid >> 6;       // 0..3 : which h-row of the tile
    const int row_l = lane & 15;
    const int grp   = lane >> 4;
    const int b7    = row_l & 7;

    // XCD-aware bijective swizzle (nwg = 1536 % 8 == 0); c innermost.
    const int raw = blockIdx.x;
    const int lb  = (raw & 7) * 192 + (raw >> 3);
    const int c    = lb & 3;
    const int wt   = (lb >> 2) % 3;
    const int hseg = (lb / 12) % 8;
    const int n    = lb / 96;
    const int w0   = wt * 64;
    const int hbase = hseg * 24;
    const int q = c & 1, p = (c >> 1) & 1;

    const short* wsrc = Wt + c * 4096;             // [t][c][j][ic], t-stride 16384

    // ---- issue helpers (vmcnt-count-uniform across waves) ----
    auto issueB = [&](int tap, int buf) {          // 2 gload_lds per wave
        #pragma unroll
        for (int r = 0; r < 2; ++r) {
            int cch = tid + r * 256;               // 0..511
            int j = cch >> 3, s = cch & 7, ss = s ^ (j & 7);
            GLOAD_LDS16(wsrc + tap * 16384 + j * 64 + ss * 8,
                        (char*)smem + B_OFF + buf * 8192 + (wv * 64 + r * 256) * 16);
        }
    };
    auto issueA = [&](int row) {                   // 3 gload_lds per wave (uniform)
        int rowc = row > 192 ? 192 : row;          // clamp (dummy tail rows -> zero halo)
        int slot = (row + 1) % NRING;              // slot from UNclamped row
        size_t rbase = ((size_t)n * 194 + (rowc + 1)) * 194;
        #pragma unroll
        for (int r = 0; r < 2; ++r) {
            int cch = wv * 132 + r * 64 + lane;    // 0..527
            int wpos = cch >> 3, g = cch & 7, gs = g ^ (wpos & 7);
            GLOAD_LDS16(xb + (rbase + (w0 + wpos)) * 64 + gs * 8,
                        (char*)smem + slot * ASLOT_B + (wv * 132 + r * 64) * 16);
        }
        if (lane < 4) {                            // 4 active lanes; still 1 instr/wave
            int cch = wv * 132 + 128 + lane;
            int wpos = cch >> 3, g = cch & 7, gs = g ^ (wpos & 7);
            GLOAD_LDS16(xb + (rbase + (w0 + wpos)) * 64 + gs * 8,
                        (char*)smem + slot * ASLOT_B + (wv * 132 + 128) * 16);
        }
    };

    // ---- prologue: B(0) -> buf0 ; A rows hbase-1 .. hbase+3 ----
    issueB(0, 0);
    #pragma unroll
    for (int r = 0; r < 5; ++r) issueA(hbase - 1 + r);
    asm volatile("s_waitcnt vmcnt(0)" ::: "memory");
    __builtin_amdgcn_sched_barrier(0);
    __syncthreads();

    f32x4 bv4[4];
    #pragma unroll
    for (int nt = 0; nt < 4; ++nt) {
        const int j0 = nt * 16 + grp * 4;
        #pragma unroll
        for (int jv = 0; jv < 4; ++jv)
            bv4[nt][jv] = bias[(j0 + jv) * 4 + c];
    }

#define TAP_HDR() \
    __builtin_amdgcn_s_barrier(); \
    __builtin_amdgcn_sched_barrier(0);
#define TAP_SYNC(VMN) \
    __builtin_amdgcn_sched_barrier(0); \
    asm volatile("s_waitcnt vmcnt(" #VMN ")" ::: "memory"); \
    __builtin_amdgcn_sched_barrier(0); \
    __builtin_amdgcn_s_barrier(); \
    __builtin_amdgcn_sched_barrier(0);

#define COMPUTE_TAP(DY, DX, BUF) { \
    const int rd = row_l + (DX); \
    const int a7 = rd & 7; \
    const int aB = sl[DY] * 4224 + rd * 64; \
    const short* bbase = smem + B_OFF / 2 + (BUF) * 4096 + row_l * 64; \
    _Pragma("unroll") for (int ks = 0; ks < 2; ++ks) { \
        const int kg = ks * 4 + grp; \
        const short* ap = &smem[aB + ((kg ^ a7) << 3)]; \
        const short* bp = bbase + ((kg ^ b7) << 3); \
        bf16x8 af[4], bfr[4]; \
        _Pragma("unroll") for (int mt = 0; mt < 4; ++mt) af[mt]  = *(const bf16x8*)(ap + mt * 1024); \
        _Pragma("unroll") for (int nt = 0; nt < 4; ++nt) bfr[nt] = *(const bf16x8*)(bp + nt * 1024); \
        _Pragma("unroll") for (int mt = 0; mt < 4; ++mt) \
            _Pragma("unroll") for (int nt = 0; nt < 4; ++nt) \
                acc[mt][nt] = __builtin_amdgcn_mfma_f32_16x16x32_bf16( \
                    bfr[nt], af[mt], acc[mt][nt], 0, 0, 0); \
    } }

    int pb = 0;
    #pragma unroll 1
    for (int it = 0; it < 6; ++it) {
        const int h0 = hbase + it * 4;

        int sl[3];
        #pragma unroll
        for (int dy = 0; dy < 3; ++dy) sl[dy] = (h0 + wv + dy) % NRING;

        f32x4 acc[4][4];
        #pragma unroll
        for (int i = 0; i < 4; ++i)
            #pragma unroll
            for (int j = 0; j < 4; ++j)
                acc[i][j] = bv4[j];

        const int pA = pb, pBb = pb ^ 1;

        // tap 0: issue B1 + A rows h0+4 (self, read taps 6-8) & h0+5 (free slot)
        TAP_HDR();
        issueB(1, pBb); issueA(h0 + 4); issueA(h0 + 5);
        TAP_SYNC(24);                    // forces B(0); stores(16)+B1(2)+A(6) in flight
        COMPUTE_TAP(0, 0, pA);
        // tap 1
        TAP_HDR();
        issueB(2, pA);
        TAP_SYNC(8);                     // forces B(1); A(6)+B2(2) in flight
        COMPUTE_TAP(0, 1, pBb);
        // tap 2
        TAP_HDR();
        issueB(3, pBb);
        TAP_SYNC(2);                     // forces B(2) + tap-0 A rows
        COMPUTE_TAP(0, 2, pA);
        // tap 3: slot of row h0-1 retired (last read tap 2 by wave 0)
        TAP_HDR();
        issueB(4, pA); issueA(h0 + 6);
        TAP_SYNC(5);                     // forces B(3); B4(2)+A(3) in flight
        COMPUTE_TAP(1, 0, pBb);
        // tap 4
        TAP_HDR();
        issueB(5, pBb);
        TAP_SYNC(5);                     // forces B(4); A(3)+B5(2) in flight
        COMPUTE_TAP(1, 1, pA);
        // tap 5
        TAP_HDR();
        issueB(6, pA);
        TAP_SYNC(2);                     // forces B(5) + A(h0+6)
        COMPUTE_TAP(1, 2, pBb);
        // tap 6: slot of row h0 retired (last read tap 5)
        TAP_HDR();
        issueB(7, pBb); issueA(h0 + 7);
        TAP_SYNC(5);                     // forces B(6) (A(h0+4) already forced)
        COMPUTE_TAP(2, 0, pA);
        // tap 7
        TAP_HDR();
        issueB(8, pA);
        TAP_SYNC(5);                     // forces B(7); A(3)+B8(2) in flight
        COMPUTE_TAP(2, 1, pBb);
        // tap 8: issue next tile's B(0) (dummy on last tile; keeps counts fixed)
        TAP_HDR();
        issueB(0, pBb);
        TAP_SYNC(2);                     // forces B(8) + A(h0+7)
        COMPUTE_TAP(2, 2, pA);

        // stores: nontemporal, fire-and-forget (16 dwordx4; forced complete by
        // next tile's tap-1 vmcnt(8) at the earliest — one tap of slack)
        {
            const int h = h0 + wv;
            const long rowb = ((long)(n * 384 + 2 * h + q)) * 384;
            #pragma unroll
            for (int mt = 0; mt < 4; ++mt) {
                float* po = out + ((rowb + 2 * (w0 + mt * 16 + row_l) + p) * 64 + grp * 4);
                #pragma unroll
                for (int nt = 0; nt < 4; ++nt)
                    __builtin_nontemporal_store(acc[mt][nt], (f32x4*)(po + nt * 16));
            }
        }

        pb ^= 1;
    }
#undef COMPUTE_TAP
#undef TAP_HDR
#undef TAP_SYNC
}

extern "C" void kernel_launch(void* const* d_in, const int* in_sizes, int n_in,
                              void* d_out, int out_size, void* d_ws, size_t ws_size,
                              hipStream_t stream) {
    const float* x = (const float*)d_in[0];
    const float* W = (const float*)d_in[1];
    const float* b = (const float*)d_in[2];
    float* out = (float*)d_out;

    const size_t xb_bytes = (size_t)16 * 194 * 194 * 64 * 2;   // 77,070,336 (padded)
    short* xbuf = (short*)d_ws;
    short* Wt   = (short*)((char*)d_ws + xb_bytes);

    hipLaunchKernelGGL(prep_kernel, dim3(2624), dim3(256), 0, stream, x, xbuf, W, Wt);
    hipLaunchKernelGGL(conv_ps_kernel, dim3(1536), dim3(256), 0, stream, xbuf, Wt, b, out);
}

// Round 15
// 223.418 us; speedup vs baseline: 1.0590x; 1.0590x over previous
//
#include <hip/hip_runtime.h>
#include <stdint.h>

typedef short bf16x8 __attribute__((ext_vector_type(8)));
typedef float f32x4  __attribute__((ext_vector_type(4)));

#define GLOAD_LDS16(gp, lp) \
    __builtin_amdgcn_global_load_lds((const __attribute__((address_space(1))) void*)(gp), \
                                     (__attribute__((address_space(3))) void*)(lp), 16, 0, 0)

__device__ __forceinline__ uint32_t bfbits(float f) {
    uint32_t u = __builtin_bit_cast(uint32_t, f);
    u += 0x7FFFu + ((u >> 16) & 1u);   // round-to-nearest-even
    return u >> 16;
}
__device__ __forceinline__ uint32_t pk2(float a, float b) {
    return bfbits(a) | (bfbits(b) << 16);
}

// Fused prep: blocks [0,2048) convert x -> xb (bf16, PADDED [16][194][194][64],
// zero halo, nontemporal x loads); blocks [2048,2624) build
// Wt[t][c][j][ic] = bf16(W[dy][dx][ic][j*4+c]).
__global__ void prep_kernel(const float* __restrict__ x, short* __restrict__ xb,
                            const float* __restrict__ W, short* __restrict__ Wt) {
    const int b = blockIdx.x;
    if (b < 2048) {
        const int total = 16 * 194 * 194 * 8;          // 16B chunks
        for (int i = b * 256 + threadIdx.x; i < total; i += 2048 * 256) {
            int g  = i & 7;
            int t  = i >> 3;
            int wp = t % 194; t /= 194;
            int hp = t % 194;
            int nn = t / 194;
            uint4 r = {0u, 0u, 0u, 0u};
            if (hp >= 1 && hp <= 192 && wp >= 1 && wp <= 192) {
                const float* s = x + (((size_t)nn * 192 + (hp - 1)) * 192 + (wp - 1)) * 64 + g * 8;
                f32x4 a = __builtin_nontemporal_load((const f32x4*)s);
                f32x4 bb = __builtin_nontemporal_load((const f32x4*)(s + 4));
                r.x = pk2(a[0], a[1]); r.y = pk2(a[2], a[3]);
                r.z = pk2(bb[0], bb[1]); r.w = pk2(bb[2], bb[3]);
            }
            *(uint4*)(xb + (size_t)i * 8) = r;
        }
    } else {
        int idx = (b - 2048) * 256 + threadIdx.x;      // 147456
        if (idx < 147456) {
            int t  = idx >> 14;
            int r  = idx & 16383;
            int c  = r >> 12;
            int j  = (r >> 6) & 63;
            int ic = r & 63;
            Wt[idx] = (short)bfbits(W[(t * 64 + ic) * 256 + j * 4 + c]);
        }
    }
}

#define NRING 7
#define ASLOT_B 8448                     // bytes per A h-row slot (66*64*2)
#define B_OFF   (NRING * ASLOT_B)        // 59,136 : B dbuf starts here
#define SMEM_SHORTS ((B_OFF + 2 * 8192) / 2)   // 75,520 B -> 2 blocks/CU

// Implicit-GEMM conv3x3 + bias + pixel_shuffle quadrant, bf16 MFMA.
// r14 structure (B per-tap stream, A-ring 7, two-barrier taps, counted vmcnt)
// + DOUBLE ACC: tile i's stores are issued 2-dwordx4-per-tap DURING tile i+1,
// each after that tap's B-issue -> forced-B waits never drain young stores,
// and store issue rate (16KB/CU/tap) < HBM drain rate (~26KB/CU/tap).
__global__ __launch_bounds__(256, 2) void conv_ps_kernel(
    const short* __restrict__ xb, const short* __restrict__ Wt,
    const float* __restrict__ bias, float* __restrict__ out)
{
    __shared__ short smem[SMEM_SHORTS];

    const int tid   = threadIdx.x;
    const int lane  = tid & 63;
    const int wv    = tid >> 6;       // 0..3 : which h-row of the tile
    const int row_l = lane & 15;
    const int grp   = lane >> 4;
    const int b7    = row_l & 7;

    // XCD-aware bijective swizzle (nwg = 1536 % 8 == 0); c innermost.
    const int raw = blockIdx.x;
    const int lb  = (raw & 7) * 192 + (raw >> 3);
    const int c    = lb & 3;
    const int wt   = (lb >> 2) % 3;
    const int hseg = (lb / 12) % 8;
    const int n    = lb / 96;
    const int w0   = wt * 64;
    const int hbase = hseg * 24;
    const int q = c & 1, p = (c >> 1) & 1;

    const short* wsrc = Wt + c * 4096;             // [t][c][j][ic], t-stride 16384

    auto issueB = [&](int tap, int buf) {          // 2 gload_lds per wave
        #pragma unroll
        for (int r = 0; r < 2; ++r) {
            int cch = tid + r * 256;               // 0..511
            int j = cch >> 3, s = cch & 7, ss = s ^ (j & 7);
            GLOAD_LDS16(wsrc + tap * 16384 + j * 64 + ss * 8,
                        (char*)smem + B_OFF + buf * 8192 + (wv * 64 + r * 256) * 16);
        }
    };
    auto issueA = [&](int row) {                   // 3 gload_lds per wave (uniform)
        int rowc = row > 192 ? 192 : row;          // clamp -> zero-halo row
        int slot = (row + 1) % NRING;
        size_t rbase = ((size_t)n * 194 + (rowc + 1)) * 194;
        #pragma unroll
        for (int r = 0; r < 2; ++r) {
            int cch = wv * 132 + r * 64 + lane;    // 0..527
            int wpos = cch >> 3, g = cch & 7, gs = g ^ (wpos & 7);
            GLOAD_LDS16(xb + (rbase + (w0 + wpos)) * 64 + gs * 8,
                        (char*)smem + slot * ASLOT_B + (wv * 132 + r * 64) * 16);
        }
        if (lane < 4) {
            int cch = wv * 132 + 128 + lane;
            int wpos = cch >> 3, g = cch & 7, gs = g ^ (wpos & 7);
            GLOAD_LDS16(xb + (rbase + (w0 + wpos)) * 64 + gs * 8,
                        (char*)smem + slot * ASLOT_B + (wv * 132 + 128) * 16);
        }
    };

    // ---- prologue: B(0) -> buf0 ; A rows hbase-1 .. hbase+3 ----
    issueB(0, 0);
    #pragma unroll
    for (int r = 0; r < 5; ++r) issueA(hbase - 1 + r);
    asm volatile("s_waitcnt vmcnt(0)" ::: "memory");
    __builtin_amdgcn_sched_barrier(0);
    __syncthreads();

    f32x4 bv4[4];
    #pragma unroll
    for (int nt = 0; nt < 4; ++nt) {
        const int j0 = nt * 16 + grp * 4;
        #pragma unroll
        for (int jv = 0; jv < 4; ++jv)
            bv4[nt][jv] = bias[(j0 + jv) * 4 + c];
    }

    f32x4 accA[4][4], accB[4][4];

#define SCHB __builtin_amdgcn_sched_barrier(0)

#define COMPUTE_TAP(ACC, DY, DX, BUF) { \
    const int rd = row_l + (DX); \
    const int a7 = rd & 7; \
    const int aB = sl[DY] * 4224 + rd * 64; \
    const short* bbase = smem + B_OFF / 2 + (BUF) * 4096 + row_l * 64; \
    _Pragma("unroll") for (int ks = 0; ks < 2; ++ks) { \
        const int kg = ks * 4 + grp; \
        const short* ap = &smem[aB + ((kg ^ a7) << 3)]; \
        const short* bp = bbase + ((kg ^ b7) << 3); \
        bf16x8 af[4], bfr[4]; \
        _Pragma("unroll") for (int mt = 0; mt < 4; ++mt) af[mt]  = *(const bf16x8*)(ap + mt * 1024); \
        _Pragma("unroll") for (int nt = 0; nt < 4; ++nt) bfr[nt] = *(const bf16x8*)(bp + nt * 1024); \
        _Pragma("unroll") for (int mt = 0; mt < 4; ++mt) \
            _Pragma("unroll") for (int nt = 0; nt < 4; ++nt) \
                ACC[mt][nt] = __builtin_amdgcn_mfma_f32_16x16x32_bf16( \
                    bfr[nt], af[mt], ACC[mt][nt], 0, 0, 0); \
    } }

// store 2 dwordx4 of the OLD acc (chunk S in 0..7)
#define ST2(ACCO, S) { \
    const int mt_ = (S) >> 1, n0_ = ((S) & 1) * 2; \
    float* po_ = out + ((rowb_o + 2 * (w0 + mt_ * 16 + row_l) + p) * 64 + grp * 4); \
    __builtin_nontemporal_store(ACCO[mt_][n0_],     (f32x4*)(po_ + n0_ * 16)); \
    __builtin_nontemporal_store(ACCO[mt_][n0_ + 1], (f32x4*)(po_ + (n0_ + 1) * 16)); }

#define TAPX(ACC, K, DY, DX, PAR, VM, EXTRA, STS) \
    __builtin_amdgcn_s_barrier(); SCHB; \
    issueB(((K) + 1) % 9, ((PAR) + (K) + 1) & 1); \
    EXTRA; SCHB; \
    STS; SCHB; \
    asm volatile("s_waitcnt vmcnt(" #VM ")" ::: "memory"); SCHB; \
    __builtin_amdgcn_s_barrier(); SCHB; \
    COMPUTE_TAP(ACC, DY, DX, ((PAR) + (K)) & 1)

#define TILE_HEAD(ACC, ITV) \
    const int h0 = hbase + (ITV) * 4; \
    int sl[3]; \
    _Pragma("unroll") for (int dy = 0; dy < 3; ++dy) sl[dy] = (h0 + wv + dy) % NRING; \
    _Pragma("unroll") for (int i = 0; i < 4; ++i) \
        _Pragma("unroll") for (int j = 0; j < 4; ++j) ACC[i][j] = bv4[j];

// steady tile: computes ACC, stores ACCO (tile ITV-1) spread 2-chunks/tap
#define STEADY_TILE(ACC, ACCO, ITV, PAR) { \
    TILE_HEAD(ACC, ITV); \
    const long rowb_o = ((long)(n * 384 + 2 * (h0 - 4 + wv) + q)) * 384; \
    TAPX(ACC, 0, 0, 0, PAR, 10, { issueA(h0 + 4); issueA(h0 + 5); }, ST2(ACCO, 0)); \
    TAPX(ACC, 1, 0, 1, PAR, 12, {}, ST2(ACCO, 1)); \
    TAPX(ACC, 2, 0, 2, PAR,  6, {}, ST2(ACCO, 2)); \
    TAPX(ACC, 3, 1, 0, PAR,  9, { issueA(h0 + 6); }, ST2(ACCO, 3)); \
    TAPX(ACC, 4, 1, 1, PAR,  9, {}, ST2(ACCO, 4)); \
    TAPX(ACC, 5, 1, 2, PAR,  6, {}, ST2(ACCO, 5)); \
    TAPX(ACC, 6, 2, 0, PAR,  9, { issueA(h0 + 7); }, ST2(ACCO, 6)); \
    TAPX(ACC, 7, 2, 1, PAR,  9, {}, ST2(ACCO, 7)); \
    TAPX(ACC, 8, 2, 2, PAR,  4, {}, {}); }

    // ---- tile 0 (peeled: no old stores; its own vmcnt set) ----
    {
        TILE_HEAD(accA, 0);
        TAPX(accA, 0, 0, 0, 0, 8, { issueA(h0 + 4); issueA(h0 + 5); }, {});
        TAPX(accA, 1, 0, 1, 0, 8, {}, {});
        TAPX(accA, 2, 0, 2, 0, 2, {}, {});
        TAPX(accA, 3, 1, 0, 0, 5, { issueA(h0 + 6); }, {});
        TAPX(accA, 4, 1, 1, 0, 5, {}, {});
        TAPX(accA, 5, 1, 2, 0, 2, {}, {});
        TAPX(accA, 6, 2, 0, 0, 5, { issueA(h0 + 7); }, {});
        TAPX(accA, 7, 2, 1, 0, 5, {}, {});
        TAPX(accA, 8, 2, 2, 0, 2, {}, {});
    }
    // ---- tiles 1..4 (pairs; parity literal per position) ----
    #pragma unroll 1
    for (int it2 = 1; it2 < 5; it2 += 2) {
        STEADY_TILE(accB, accA, it2, 1);
        STEADY_TILE(accA, accB, it2 + 1, 0);
    }
    // ---- tile 5 ----
    STEADY_TILE(accB, accA, 5, 1);
    // ---- final: store tile 5's acc directly ----
    {
        const int h = hbase + 20 + wv;
        const long rowb = ((long)(n * 384 + 2 * h + q)) * 384;
        #pragma unroll
        for (int mt = 0; mt < 4; ++mt) {
            float* po = out + ((rowb + 2 * (w0 + mt * 16 + row_l) + p) * 64 + grp * 4);
            #pragma unroll
            for (int nt = 0; nt < 4; ++nt)
                __builtin_nontemporal_store(accB[mt][nt], (f32x4*)(po + nt * 16));
        }
    }
#undef STEADY_TILE
#undef TILE_HEAD
#undef TAPX
#undef ST2
#undef COMPUTE_TAP
#undef SCHB
}

extern "C" void kernel_launch(void* const* d_in, const int* in_sizes, int n_in,
                              void* d_out, int out_size, void* d_ws, size_t ws_size,
                              hipStream_t stream) {
    const float* x = (const float*)d_in[0];
    const float* W = (const float*)d_in[1];
    const float* b = (const float*)d_in[2];
    float* out = (float*)d_out;

    const size_t xb_bytes = (size_t)16 * 194 * 194 * 64 * 2;   // 77,070,336 (padded)
    short* xbuf = (short*)d_ws;
    short* Wt   = (short*)((char*)d_ws + xb_bytes);

    hipLaunchKernelGGL(prep_kernel, dim3(2624), dim3(256), 0, stream, x, xbuf, W, Wt);
    hipLaunchKernelGGL(conv_ps_kernel, dim3(1536), dim3(256), 0, stream, xbuf, Wt, b, out);
}